// Round 4
// baseline (209.954 us; speedup 1.0000x reference)
//
#include <hip/hip_runtime.h>
#include <stdint.h>

// out[n,k,y,x] = sum_c grid[n,k,c,y/16,x/16] * guidemap[n,c,y,x]
// N=2, K=C=32, H=W=1024, 64x64 tiles of 16x16 px.
//
// R4: SGPR-broadcast design.
//  Pass 1: transpose grid -> ws[tile][c][k] (128B-contiguous per (tile,c)).
//  Pass 2: per-tile 32x32x256 SGEMM with M in SGPRs via s_load_dwordx16
//          (double-buffered, paired issue + lgkmcnt(0)), guide streamed
//          global->reg float4 4-deep. No LDS, no barriers in hot loop.

namespace {
constexpr int K = 32, C = 32;
constexpr int W = 1024;
constexpr int HW = 1024 * 1024;
constexpr size_t GRDN = (size_t)K * C * 64 * 64;     // floats per image
constexpr size_t WS_BYTES = (size_t)8192 * 1024 * 4; // 33.5 MB
}

typedef float f32x16 __attribute__((ext_vector_type(16)));

// ---------- pass 1: grd [n][k][c][64][64] -> ws [tile][c][k] ----------
__global__ __launch_bounds__(256) void mat_transpose_kernel(
    const float* __restrict__ grd, float* __restrict__ ws)
{
    int wg = blockIdx.x;
    wg = (wg & 7) * 1024 + (wg >> 3);   // XCD x owns tiles [x*1024,(x+1)*1024)
    const int t = threadIdx.x;
    const int n  = wg >> 12;
    const int rr = wg & 4095;
    const int by = rr >> 6, bx = rr & 63;
    const float* g = grd + (size_t)n * GRDN + by * 64 + bx;
    const int e0 = t * 4;           // e = c*32 + k
    const int c  = e0 >> 5;
    const int k0 = e0 & 31;         // 0,4,...,28 (same c for all 4)
    float4 v;
    v.x = g[(size_t)((k0 + 0) * 32 + c) * 4096];
    v.y = g[(size_t)((k0 + 1) * 32 + c) * 4096];
    v.z = g[(size_t)((k0 + 2) * 32 + c) * 4096];
    v.w = g[(size_t)((k0 + 3) * 32 + c) * 4096];
    *reinterpret_cast<float4*>(ws + (size_t)wg * 1024 + e0) = v;
}

// ---------- pass 2: main ----------
__global__ __launch_bounds__(256, 4) void gridup_main(
    const float* __restrict__ ws,    // [8192][32][32]
    const float* __restrict__ gm,    // [N][C][1024][1024]
    float* __restrict__ out)         // [N][K][1024][1024]
{
    const int b  = blockIdx.x;
    const int wg = (b & 7) * 512 + (b >> 3);   // XCD-contiguous tile pairs
    const int t  = threadIdx.x;
    const int w  = t >> 6;
    const int tl = w >> 1;          // which tile of the pair
    const int kh = w & 1;           // k half: 0 -> k 0..15, 1 -> k 16..31
    const int l  = t & 63;

    const int gt = wg * 2 + tl;
    const int n  = gt >> 12;
    const int rr = gt & 4095;
    const int by = rr >> 6, bx = rr & 63;

    const int row = l >> 2, col4 = (l & 3) << 2;
    const size_t pix = (size_t)(by * 16 + row) * W + bx * 16 + col4;
    const float* gb = gm + (size_t)n * C * HW + pix;
    float* ob = out + ((size_t)n * K + kh * 16) * HW + pix;

    // Wave-uniform M base; readfirstlane so inline asm gets a clean SGPR pair.
    const uint64_t a = (uint64_t)(ws + (size_t)gt * 1024 + kh * 16);
    const uint32_t alo = __builtin_amdgcn_readfirstlane((uint32_t)a);
    const uint32_t ahi = __builtin_amdgcn_readfirstlane((uint32_t)(a >> 32));
    const uint64_t mp = ((uint64_t)ahi << 32) | alo;

    // Prologue: issue M for c=0 (off 0) and c=1 (off 128B).
    f32x16 mA, mB;
    asm volatile("s_load_dwordx16 %0, %2, 0\n\t"
                 "s_load_dwordx16 %1, %2, 128"
                 : "=s"(mA), "=s"(mB)
                 : "s"(mp));

    // Guide ring, 4 deep.
    float4 g[4];
#pragma unroll
    for (int j = 0; j < 4; ++j)
        g[j] = *reinterpret_cast<const float4*>(gb + (size_t)j * HW);

    float acc[16][4] = {};

#pragma unroll
    for (int cp = 0; cp < 16; ++cp) {          // c = 2cp, 2cp+1
        // Wait for this pair's M; data-dep via "+s" stops hoisting (rule #18).
        asm volatile("s_waitcnt lgkmcnt(0)" : "+s"(mA), "+s"(mB) :: "memory");
        const f32x16 fA = mA, fB = mB;         // SALU copies free the buffers
        if (cp < 15) {                         // issue next pair early
            asm volatile("s_load_dwordx16 %0, %2, %3\n\t"
                         "s_load_dwordx16 %1, %2, %4"
                         : "=s"(mA), "=s"(mB)
                         : "s"(mp), "i"((2 * cp + 2) * 128),
                                    "i"((2 * cp + 3) * 128));
        }
        const float4 gv0 = g[(2 * cp) & 3];
        const float4 gv1 = g[(2 * cp + 1) & 3];
        if (2 * cp + 4 < 32)
            g[(2 * cp) & 3] = *reinterpret_cast<const float4*>(
                gb + (size_t)(2 * cp + 4) * HW);
        if (2 * cp + 5 < 32)
            g[(2 * cp + 1) & 3] = *reinterpret_cast<const float4*>(
                gb + (size_t)(2 * cp + 5) * HW);
#pragma unroll
        for (int k = 0; k < 16; ++k) {
            acc[k][0] += fA[k] * gv0.x;  acc[k][1] += fA[k] * gv0.y;
            acc[k][2] += fA[k] * gv0.z;  acc[k][3] += fA[k] * gv0.w;
        }
#pragma unroll
        for (int k = 0; k < 16; ++k) {
            acc[k][0] += fB[k] * gv1.x;  acc[k][1] += fB[k] * gv1.y;
            acc[k][2] += fB[k] * gv1.z;  acc[k][3] += fB[k] * gv1.w;
        }
    }

#pragma unroll
    for (int k = 0; k < 16; ++k) {
        const float4 v = {acc[k][0], acc[k][1], acc[k][2], acc[k][3]};
        *reinterpret_cast<float4*>(ob + (size_t)k * HW) = v;
    }
}

// ---------- fallback (proven R3 kernel) if ws too small ----------
__device__ __forceinline__ void gl_lds4(const float* src, float* dst) {
    __builtin_amdgcn_global_load_lds(
        (const __attribute__((address_space(1))) void*)src,
        (__attribute__((address_space(3))) void*)dst, 4, 0, 0);
}

__global__ __launch_bounds__(256, 4) void gridup_fb(
    const float* __restrict__ grd, const float* __restrict__ gm,
    float* __restrict__ out)
{
    __shared__ float sM[2][C][K];
    int wg = blockIdx.x;
    wg = (wg & 7) * 512 + (wg >> 3);
    const int t = threadIdx.x;
    const int g0 = wg * 2;
#pragma unroll
    for (int i = 0; i < 8; ++i) {
        const int e = i * 256 + t;
        const int t2 = e >> 10, c = (e >> 5) & 31, k = e & 31;
        const int gt2 = g0 + t2, n2 = gt2 >> 12, rr2 = gt2 & 4095;
        gl_lds4(grd + (size_t)n2 * GRDN + (size_t)(k * 32 + c) * 4096 +
                    (rr2 >> 6) * 64 + (rr2 & 63),
                &sM[0][0][0] + e);
    }
    __syncthreads();
    const int tl = t >> 7;
    const int gt = g0 + tl, n = gt >> 12, rr = gt & 4095;
    const int by = rr >> 6, bx = rr & 63;
    const float* M = &sM[tl][0][0];
    const int p = (t & 127) * 2, row = p >> 4, col = p & 15;
    const size_t pix = (size_t)(by * 16 + row) * W + bx * 16 + col;
    const float* gb = gm + (size_t)n * C * HW + pix;
    float* ob = out + (size_t)n * K * HW + pix;
    float acc[32][2] = {};
    float2 gc[4], gn[4];
#pragma unroll
    for (int j = 0; j < 4; ++j)
        gc[j] = *reinterpret_cast<const float2*>(gb + (size_t)j * HW);
    for (int cb = 0; cb < 8; ++cb) {
        if (cb < 7) {
#pragma unroll
            for (int j = 0; j < 4; ++j)
                gn[j] = *reinterpret_cast<const float2*>(
                    gb + (size_t)((cb + 1) * 4 + j) * HW);
        }
#pragma unroll
        for (int j = 0; j < 4; ++j) {
            const int c = cb * 4 + j;
            const float2 gv = gc[j];
#pragma unroll
            for (int kq = 0; kq < 8; ++kq) {
                const float4 m = *reinterpret_cast<const float4*>(M + c * 32 + kq * 4);
                acc[kq * 4 + 0][0] += m.x * gv.x; acc[kq * 4 + 0][1] += m.x * gv.y;
                acc[kq * 4 + 1][0] += m.y * gv.x; acc[kq * 4 + 1][1] += m.y * gv.y;
                acc[kq * 4 + 2][0] += m.z * gv.x; acc[kq * 4 + 2][1] += m.z * gv.y;
                acc[kq * 4 + 3][0] += m.w * gv.x; acc[kq * 4 + 3][1] += m.w * gv.y;
            }
        }
        if (cb < 7) {
#pragma unroll
            for (int j = 0; j < 4; ++j) gc[j] = gn[j];
        }
    }
#pragma unroll
    for (int k = 0; k < 32; ++k) {
        const float2 v = {acc[k][0], acc[k][1]};
        *reinterpret_cast<float2*>(ob + (size_t)k * HW) = v;
    }
}

extern "C" void kernel_launch(void* const* d_in, const int* in_sizes, int n_in,
                              void* d_out, int out_size, void* d_ws, size_t ws_size,
                              hipStream_t stream) {
    const float* grd = (const float*)d_in[0];   // grid:     2*32*32*64*64
    const float* gm  = (const float*)d_in[1];   // guidemap: 2*32*1024*1024
    float* out = (float*)d_out;                 // 2*32*1024*1024 fp32

    if (ws_size >= WS_BYTES) {
        float* ws = (float*)d_ws;
        mat_transpose_kernel<<<8192, 256, 0, stream>>>(grd, ws);
        gridup_main<<<4096, 256, 0, stream>>>(ws, gm, out);
    } else {
        gridup_fb<<<4096, 256, 0, stream>>>(grd, gm, out);
    }
}

// Round 5
// 208.561 us; speedup vs baseline: 1.0067x; 1.0067x over previous
//
#include <hip/hip_runtime.h>

// out[n,k,y,x] = sum_c grid[n,k,c,y/16,x/16] * guidemap[n,c,y,x]
// N=2, K=C=32, H=W=1024, 64x64 tiles of 16x16 px.
//
// R5: full-cache-line access design.
//  - WG = 256 thr = one PAIR of horizontally adjacent tiles (32x16 px).
//  - Wave = 8 rows x 32 px: every guide load and out store is 8 FULL 128B
//    lines (previous rounds used 64B half-lines -> ~3 TB/s plateau).
//  - Waves in WG: rowhalf x khalf. Only the two 32x32 matrices go to LDS
//    (8 KB, staged once via global_load_lds, single barrier).
//  - Hot loop: 4x ds_read_b128 (2 addrs 4KB apart = same-bank 2-way, free)
//    + float4 guide ring (4 deep) + 64 FMA per channel.

namespace {
constexpr int K = 32, C = 32;
constexpr int W = 1024;
constexpr int HW = 1024 * 1024;
constexpr size_t GRDN = (size_t)K * C * 64 * 64;  // floats per image
}

__device__ __forceinline__ void gl_lds4(const float* src, float* dst) {
    __builtin_amdgcn_global_load_lds(
        (const __attribute__((address_space(1))) void*)src,
        (__attribute__((address_space(3))) void*)dst, 4, 0, 0);
}

__global__ __launch_bounds__(256, 4) void gridup_kernel(
    const float* __restrict__ grd,   // [N][K][C][64][64]
    const float* __restrict__ gm,    // [N][C][1024][1024]
    float* __restrict__ out)         // [N][K][1024][1024]
{
    __shared__ float sM[2][C][K];    // [bxp][c][k], 8 KB

    const int b  = blockIdx.x;
    const int tp = (b & 7) * 512 + (b >> 3);  // XCD-contiguous tile-pairs
    const int t  = threadIdx.x;

    const int gt0 = tp * 2;                   // even tile; pair shares n,by
    const int n   = gt0 >> 12;
    const int rr  = gt0 & 4095;
    const int by  = rr >> 6;
    const int bx0 = rr & 63;                  // even

    // ---- stage both matrices: e = [bxp][c][k] linear, 4B gathers
    #pragma unroll
    for (int i = 0; i < 8; ++i) {
        const int e   = i * 256 + t;          // 0..2047
        const int bxp = e >> 10;
        const int c   = (e >> 5) & 31;
        const int k   = e & 31;
        gl_lds4(grd + (size_t)n * GRDN + (size_t)(k * 32 + c) * 4096 +
                    by * 64 + bx0 + bxp,
                &sM[0][0][0] + e);
    }
    __syncthreads();   // only barrier in the kernel

    const int l  = t & 63;
    const int w  = t >> 6;
    const int rh = w & 1;    // row half: rows 0-7 / 8-15
    const int kh = w >> 1;   // k half:   k 0-15 / 16-31

    const int r    = l >> 3;        // 0..7
    const int bxp  = (l >> 2) & 1;  // which tile of the pair
    const int cq   = l & 3;         // float4 column within 16px

    const int row   = by * 16 + rh * 8 + r;
    const int colpx = (bx0 + bxp) * 16 + cq * 4;
    const float* gb = gm + (size_t)n * C * HW + (size_t)row * W + colpx;
    float*       ob = out + ((size_t)n * K + kh * 16) * HW + (size_t)row * W + colpx;
    const float* Mb = &sM[bxp][0][kh * 16];

    // Guide ring, 4 deep.
    float4 g[4];
    #pragma unroll
    for (int j = 0; j < 4; ++j)
        g[j] = *reinterpret_cast<const float4*>(gb + (size_t)j * HW);

    float acc[16][4] = {};

    #pragma unroll
    for (int c = 0; c < C; ++c) {
        const float4 gv = g[c & 3];
        if (c + 4 < C)
            g[c & 3] = *reinterpret_cast<const float4*>(gb + (size_t)(c + 4) * HW);
        #pragma unroll
        for (int kq = 0; kq < 4; ++kq) {
            const float4 m = *reinterpret_cast<const float4*>(Mb + c * K + kq * 4);
            acc[kq * 4 + 0][0] += m.x * gv.x;  acc[kq * 4 + 0][1] += m.x * gv.y;
            acc[kq * 4 + 0][2] += m.x * gv.z;  acc[kq * 4 + 0][3] += m.x * gv.w;
            acc[kq * 4 + 1][0] += m.y * gv.x;  acc[kq * 4 + 1][1] += m.y * gv.y;
            acc[kq * 4 + 1][2] += m.y * gv.z;  acc[kq * 4 + 1][3] += m.y * gv.w;
            acc[kq * 4 + 2][0] += m.z * gv.x;  acc[kq * 4 + 2][1] += m.z * gv.y;
            acc[kq * 4 + 2][2] += m.z * gv.z;  acc[kq * 4 + 2][3] += m.z * gv.w;
            acc[kq * 4 + 3][0] += m.w * gv.x;  acc[kq * 4 + 3][1] += m.w * gv.y;
            acc[kq * 4 + 3][2] += m.w * gv.z;  acc[kq * 4 + 3][3] += m.w * gv.w;
        }
    }

    // ---- stores: per k, wave covers 8 rows x 32px = 8 full 128B lines
    #pragma unroll
    for (int k = 0; k < 16; ++k) {
        const float4 v = {acc[k][0], acc[k][1], acc[k][2], acc[k][3]};
        *reinterpret_cast<float4*>(ob + (size_t)k * HW) = v;
    }
}

extern "C" void kernel_launch(void* const* d_in, const int* in_sizes, int n_in,
                              void* d_out, int out_size, void* d_ws, size_t ws_size,
                              hipStream_t stream) {
    const float* grd = (const float*)d_in[0];   // grid:     2*32*32*64*64
    const float* gm  = (const float*)d_in[1];   // guidemap: 2*32*1024*1024
    float* out = (float*)d_out;                 // 2*32*1024*1024 fp32

    gridup_kernel<<<4096, 256, 0, stream>>>(grd, gm, out);
}